// Round 12
// baseline (381.639 us; speedup 1.0000x reference)
//
#include <hip/hip_runtime.h>
#include <hip/hip_bf16.h>

typedef __attribute__((ext_vector_type(4))) float f32x4;
typedef __attribute__((ext_vector_type(8))) short bf16x8;
typedef __attribute__((ext_vector_type(8))) unsigned short us8;
typedef __attribute__((ext_vector_type(4))) unsigned short us4;

__device__ __forceinline__ float bf2f(unsigned short u) {
    union { unsigned int i; float f; } x; x.i = ((unsigned int)u) << 16; return x.f;
}
__device__ __forceinline__ unsigned short f2bf(float f) {
    union { float f; unsigned int i; } x; x.f = f;
    unsigned int i = x.i;
    return (unsigned short)((i + 0x7FFFu + ((i >> 16) & 1u)) >> 16);
}

// ---------------- build Wt[1024][256] bf16 (transposed), biases, gate vecs ----------------
__global__ void k_conv_w(const float* __restrict__ Wq, const float* __restrict__ Wk,
                         const float* __restrict__ Wv, const float* __restrict__ Ws,
                         const float* __restrict__ bq, const float* __restrict__ bk,
                         const float* __restrict__ bv, const float* __restrict__ bs,
                         const float* __restrict__ Wg,
                         unsigned short* __restrict__ Wt, float* __restrict__ ball,
                         float* __restrict__ wga, float* __restrict__ wgb)
{
    int gid = blockIdx.x * 256 + threadIdx.x;  // 65536 threads
    int k = gid >> 8, colq = gid & 255;
    int col0 = colq * 4;
    const float* Wsel[4] = {Wq, Wk, Wv, Ws};
    const float* W = Wsel[col0 >> 8];
    int c0 = col0 & 255;
    f32x4 w = *(const f32x4*)(W + k * 256 + c0);
    for (int j = 0; j < 4; ++j)
        Wt[(size_t)(col0 + j) * 256 + k] = f2bf(w[j]);
    if (gid < 1024) {
        const float* bsel[4] = {bq, bk, bv, bs};
        ball[gid] = bsel[gid >> 8][gid & 255];
    } else if (gid < 1280) {
        int i = gid - 1024;
        wga[i] = Wg[i] + Wg[512 + i];          // coeff on skip
    } else if (gid < 1536) {
        int i = gid - 1280;
        wgb[i] = Wg[256 + i] - Wg[512 + i];    // coeff on rst
    }
}

// ---------------- fused QKV+skip GEMM: feat fp32 [M,256] x Wt [256,1024] ----------------
// Each block computes TWO bn-tiles (A staged once per k0 -> A L3-reread traffic halved).
// qkvb row layout is q|v|k (gather touches only first 1024B of each 1536B row).
// Epilogue: 2 output buffers, dense 256B spans per (block,row) - the R8-proven shape.
#define BM 128
#define BN 128
#define BK 64
#define SST 72   // LDS row stride in bf16: 144B = 16B-aligned, bank-step 4 -> conflict-free

__global__ __launch_bounds__(256) void k_gemm(
    const float* __restrict__ A, const unsigned short* __restrict__ Bt,
    const float* __restrict__ bias, unsigned short* __restrict__ qkvb,
    float* __restrict__ skipf, int M)
{
    __shared__ unsigned short a_sm[BM * SST];
    __shared__ unsigned short b_sm[BN * SST];
    int id = blockIdx.x;
    int bg = id & 3, bm = id >> 2;       // bg -> bn pair {2bg, 2bg+1}
    int t = threadIdx.x;
    int lane = t & 63, wid = t >> 6;
    int wr = wid >> 1, wc = wid & 1;
    int l15 = lane & 15, l4 = lane >> 4;
    f32x4 acc[2][4][4] = {};
    for (int k0 = 0; k0 < 256; k0 += BK) {
        // stage A once per k0 (protected by trailing sync of previous iteration)
        for (int it = 0; it < 4; ++it) {
            int c = it * 256 + t;
            int row = c >> 3;
            int ko = (c & 7) * 8;
            int grow = bm * BM + row;
            if (grow >= M) grow = M - 1;
            const f32x4* pa = (const f32x4*)(A + (size_t)grow * 256 + k0 + ko);
            f32x4 x = pa[0], y = pa[1];
            us8 o;
            o[0] = f2bf(x[0]); o[1] = f2bf(x[1]); o[2] = f2bf(x[2]); o[3] = f2bf(x[3]);
            o[4] = f2bf(y[0]); o[5] = f2bf(y[1]); o[6] = f2bf(y[2]); o[7] = f2bf(y[3]);
            *(us8*)(a_sm + row * SST + ko) = o;
        }
        for (int t2 = 0; t2 < 2; ++t2) {
            int bn = bg * 2 + t2;
            for (int it = 0; it < 4; ++it) {
                int c = it * 256 + t;
                int row = c >> 3;
                int ko = (c & 7) * 8;
                int gcol = bn * BN + row;
                us8 vb = *(const us8*)(Bt + (size_t)gcol * 256 + k0 + ko);
                *(us8*)(b_sm + row * SST + ko) = vb;
            }
            __syncthreads();
            for (int kk = 0; kk < BK; kk += 32) {
                bf16x8 af[4], bf[4];
                for (int mi = 0; mi < 4; ++mi)
                    af[mi] = *(const bf16x8*)(a_sm + (wr * 64 + mi * 16 + l15) * SST + kk + l4 * 8);
                for (int ni = 0; ni < 4; ++ni)
                    bf[ni] = *(const bf16x8*)(b_sm + (wc * 64 + ni * 16 + l15) * SST + kk + l4 * 8);
                for (int mi = 0; mi < 4; ++mi)
                    for (int ni = 0; ni < 4; ++ni)
                        acc[t2][mi][ni] = __builtin_amdgcn_mfma_f32_16x16x32_bf16(af[mi], bf[ni], acc[t2][mi][ni], 0, 0, 0);
            }
            __syncthreads();
        }
    }
    for (int t2 = 0; t2 < 2; ++t2) {
        int bn = bg * 2 + t2;
        int colb = bn * BN + wc * 64 + l15;
        for (int mi = 0; mi < 4; ++mi) {
            int rowb = bm * BM + wr * 64 + mi * 16 + l4 * 4;
            for (int ni = 0; ni < 4; ++ni) {
                int col = colb + ni * 16;
                float bv = bias[col];
                // column reorder q|v|k: q stays, k 256-511 -> 512-767, v 512-767 -> 256-511
                int ocol = (col < 256) ? col : (col < 512) ? col + 256 : (col < 768) ? col - 256 : col;
                for (int r = 0; r < 4; ++r) {
                    int row = rowb + r;
                    if (row < M) {
                        float v = acc[t2][mi][ni][r] + bv;
                        if (col < 768) qkvb[(size_t)row * 768 + ocol] = f2bf(v);
                        else skipf[(size_t)row * 256 + (col - 768)] = v;
                    }
                }
            }
        }
    }
}

// ---------------- CSR build ----------------
__global__ void k_count(const int* __restrict__ dst, int* __restrict__ cnt, int e) {
    int t = blockIdx.x * 256 + threadIdx.x;
    if (t < e) atomicAdd(&cnt[dst[t]], 1);
}
__global__ void k_scan1(const int* __restrict__ cnt, int* __restrict__ inc, int* __restrict__ bsum, int n) {
    int t = threadIdx.x;
    int i = blockIdx.x * 256 + t;
    int lane = t & 63, w = t >> 6;
    int v = (i < n) ? cnt[i] : 0;
    int s = v;
    for (int off = 1; off < 64; off <<= 1) {
        int u = __shfl_up(s, off, 64);
        if (lane >= off) s += u;
    }
    __shared__ int wt[4];
    if (lane == 63) wt[w] = s;
    __syncthreads();
    for (int j = 0; j < w; ++j) s += wt[j];
    if (i < n) inc[i] = s;
    if (t == 255) bsum[blockIdx.x] = s;
}
__global__ void k_scan2(int* __restrict__ bsum, int nb) {
    int t = threadIdx.x;
    int lane = t & 63, w = t >> 6;
    int v = (t < nb) ? bsum[t] : 0;
    int s = v;
    for (int off = 1; off < 64; off <<= 1) {
        int u = __shfl_up(s, off, 64);
        if (lane >= off) s += u;
    }
    __shared__ int wt[4];
    if (lane == 63) wt[w] = s;
    __syncthreads();
    for (int j = 0; j < w; ++j) s += wt[j];
    if (t < nb) bsum[t] = s - v;
}
__global__ void k_scan3(const int* __restrict__ cnt, int* __restrict__ rowstart, const int* __restrict__ bsum, int n, int e) {
    int i = blockIdx.x * 256 + threadIdx.x;
    if (i < n) rowstart[i] = bsum[blockIdx.x] + rowstart[i] - cnt[i];
    if (i == 0) rowstart[n] = e;
}
__global__ void k_scatter(const int* __restrict__ src, const int* __restrict__ dst,
                          const int* __restrict__ rowstart, int* __restrict__ cur,
                          int* __restrict__ esrc, int e) {
    int t = blockIdx.x * 256 + threadIdx.x;
    if (t < e) {
        int d = dst[t];
        int pos = rowstart[d] + atomicAdd(&cur[d], 1);
        esrc[pos] = src[t];
    }
}

// ---------------- fused attn + gate + LN + PReLU: one wave per dst node ----------------
__device__ __forceinline__ float dot4k(us4 q, const float* kf) {
    return bf2f(q[0]) * kf[0] + bf2f(q[1]) * kf[1] + bf2f(q[2]) * kf[2] + bf2f(q[3]) * kf[3];
}
__device__ __forceinline__ float red16(float sc) {
    sc += __shfl_xor(sc, 1, 16);
    sc += __shfl_xor(sc, 2, 16);
    sc += __shfl_xor(sc, 4, 16);
    sc += __shfl_xor(sc, 8, 16);
    return sc;
}

__global__ void k_attn(const unsigned short* __restrict__ qkvb,
                       const float* __restrict__ skipf,
                       const int* __restrict__ rowstart, const int* __restrict__ esrc,
                       const float* __restrict__ wga, const float* __restrict__ wgb,
                       const float* __restrict__ bgp, const float* __restrict__ lns,
                       const float* __restrict__ lnb, const float* __restrict__ alphap,
                       float* __restrict__ out, int n)
{
    int node = blockIdx.x * 4 + (threadIdx.x >> 6);
    if (node >= n) return;
    int lane = threadIdx.x & 63;
    int lane4 = lane * 4;
    // row layout q|v|k: k for this node at offset 512
    us4 k4 = __builtin_nontemporal_load((const us4*)(qkvb + (size_t)node * 768 + 512 + lane4));
    float kf[4];
    for (int i = 0; i < 4; ++i) kf[i] = bf2f(k4[i]);
    int p0 = rowstart[node], p1 = rowstart[node + 1];
    float denom = 0.f;
    f32x4 acc = {0.f, 0.f, 0.f, 0.f};
    int p = p0;
    for (; p + 8 <= p1; p += 8) {
        int sidx[8];
        #pragma unroll
        for (int j = 0; j < 8; ++j) sidx[j] = esrc[p + j];
        us4 q[8], v[8];
        #pragma unroll
        for (int j = 0; j < 8; ++j) {
            const unsigned short* r = qkvb + (size_t)sidx[j] * 768 + lane4;
            q[j] = *(const us4*)(r);
            v[j] = *(const us4*)(r + 256);
        }
        float a[8];
        #pragma unroll
        for (int j = 0; j < 8; ++j)
            a[j] = __expf(red16(dot4k(q[j], kf)) * 0.125f);
        #pragma unroll
        for (int j = 0; j < 8; ++j) {
            denom += a[j];
            for (int i = 0; i < 4; ++i) acc[i] += a[j] * bf2f(v[j][i]);
        }
    }
    for (; p + 4 <= p1; p += 4) {
        int sidx[4];
        #pragma unroll
        for (int j = 0; j < 4; ++j) sidx[j] = esrc[p + j];
        us4 q[4], v[4];
        #pragma unroll
        for (int j = 0; j < 4; ++j) {
            const unsigned short* r = qkvb + (size_t)sidx[j] * 768 + lane4;
            q[j] = *(const us4*)(r);
            v[j] = *(const us4*)(r + 256);
        }
        float a[4];
        #pragma unroll
        for (int j = 0; j < 4; ++j)
            a[j] = __expf(red16(dot4k(q[j], kf)) * 0.125f);
        #pragma unroll
        for (int j = 0; j < 4; ++j) {
            denom += a[j];
            for (int i = 0; i < 4; ++i) acc[i] += a[j] * bf2f(v[j][i]);
        }
    }
    for (; p < p1; ++p) {
        int s = esrc[p];
        const unsigned short* r = qkvb + (size_t)s * 768 + lane4;
        us4 q4 = *(const us4*)(r);
        us4 v4 = *(const us4*)(r + 256);
        float sc = red16(dot4k(q4, kf));
        float a = __expf(sc * 0.125f);
        denom += a;
        for (int i = 0; i < 4; ++i) acc[i] += a * bf2f(v4[i]);
    }
    float inv = denom > 0.f ? 1.f / denom : 0.f;
    float rst[4];
    for (int i = 0; i < 4; ++i) rst[i] = acc[i] * inv;

    // ---- gate + LN + PReLU (fused epilogue) ----
    f32x4 sk = __builtin_nontemporal_load((const f32x4*)(skipf + (size_t)node * 256 + lane4));
    f32x4 ga = *(const f32x4*)(wga + lane4);
    f32x4 gb = *(const f32x4*)(wgb + lane4);
    float g = 0.f;
    for (int i = 0; i < 4; ++i) g += sk[i] * ga[i] + rst[i] * gb[i];
    for (int off = 1; off < 64; off <<= 1) g += __shfl_xor(g, off, 64);
    float gate = 1.f / (1.f + __expf(-(g + bgp[0])));
    float r[4], s1v = 0.f, s2v = 0.f;
    for (int i = 0; i < 4; ++i) {
        r[i] = gate * sk[i] + (1.f - gate) * rst[i];
        s1v += r[i]; s2v += r[i] * r[i];
    }
    for (int off = 1; off < 64; off <<= 1) {
        s1v += __shfl_xor(s1v, off, 64);
        s2v += __shfl_xor(s2v, off, 64);
    }
    float mean = s1v * (1.f / 256.f);
    float var = s2v * (1.f / 256.f) - mean * mean;
    float rsig = rsqrtf(var + 1e-5f);
    f32x4 sc4 = *(const f32x4*)(lns + lane4);
    f32x4 bi4 = *(const f32x4*)(lnb + lane4);
    float alpha = alphap[0];
    f32x4 y;
    for (int i = 0; i < 4; ++i) {
        float v = (r[i] - mean) * rsig * sc4[i] + bi4[i];
        y[i] = v > 0.f ? v : alpha * v;
    }
    __builtin_nontemporal_store(y, (f32x4*)(out + (size_t)node * 256 + lane4));
}

extern "C" void kernel_launch(void* const* d_in, const int* in_sizes, int n_in,
                              void* d_out, int out_size, void* d_ws, size_t ws_size,
                              hipStream_t stream)
{
    const float* feat = (const float*)d_in[0];
    const int* src = (const int*)d_in[1];
    const int* dst = (const int*)d_in[2];
    const float* Wq = (const float*)d_in[3];
    const float* bq = (const float*)d_in[4];
    const float* Wk = (const float*)d_in[5];
    const float* bk = (const float*)d_in[6];
    const float* Wv = (const float*)d_in[7];
    const float* bv = (const float*)d_in[8];
    const float* Ws = (const float*)d_in[9];
    const float* bs = (const float*)d_in[10];
    const float* Wg = (const float*)d_in[11];
    const float* bg = (const float*)d_in[12];
    const float* lns = (const float*)d_in[13];
    const float* lnb = (const float*)d_in[14];
    const float* alpha = (const float*)d_in[15];
    int N = in_sizes[0] / 256;
    int E = in_sizes[1];

    char* w = (char*)d_ws;
    size_t off = 0;
    auto alloc = [&](size_t b) { char* p = w + off; off += (b + 255) & ~(size_t)255; return p; };
    unsigned short* Wt    = (unsigned short*)alloc((size_t)1024 * 256 * 2);
    float* ball = (float*)alloc(1024 * 4);
    float* wga  = (float*)alloc(256 * 4);
    float* wgb  = (float*)alloc(256 * 4);
    unsigned short* qkvb = (unsigned short*)alloc((size_t)N * 768 * 2);
    float* skipf = (float*)alloc((size_t)N * 256 * 4);
    int* cnt = (int*)alloc((size_t)N * 4);
    int* rowstart = (int*)alloc(((size_t)N + 1) * 4);
    int* bsum = (int*)alloc(256 * 4);
    int* esrc = (int*)alloc((size_t)E * 4);
    float* outf = (float*)d_out;

    hipMemsetAsync(cnt, 0, (size_t)N * 4, stream);

    k_conv_w<<<256, 256, 0, stream>>>(Wq, Wk, Wv, Ws, bq, bk, bv, bs, Wg, Wt, ball, wga, wgb);

    int MB = (N + BM - 1) / BM;                    // 391
    k_gemm<<<MB * 4, 256, 0, stream>>>(feat, Wt, ball, qkvb, skipf, N);

    int eb = (E + 255) / 256;
    k_count<<<eb, 256, 0, stream>>>(dst, cnt, E);
    int nb = (N + 255) / 256;
    k_scan1<<<nb, 256, 0, stream>>>(cnt, rowstart, bsum, N);
    k_scan2<<<1, 256, 0, stream>>>(bsum, nb);
    k_scan3<<<nb, 256, 0, stream>>>(cnt, rowstart, bsum, N, E);
    hipMemsetAsync(cnt, 0, (size_t)N * 4, stream);
    k_scatter<<<eb, 256, 0, stream>>>(src, dst, rowstart, cnt, esrc, E);

    k_attn<<<(N + 3) / 4, 256, 0, stream>>>(qkvb, skipf, rowstart, esrc,
                                            wga, wgb, bg, lns, lnb, alpha, outf, N);
}

// Round 13
// 304.102 us; speedup vs baseline: 1.2550x; 1.2550x over previous
//
#include <hip/hip_runtime.h>
#include <hip/hip_bf16.h>

typedef __attribute__((ext_vector_type(4))) float f32x4;
typedef __attribute__((ext_vector_type(8))) short bf16x8;
typedef __attribute__((ext_vector_type(8))) unsigned short us8;
typedef __attribute__((ext_vector_type(4))) unsigned short us4;

__device__ __forceinline__ float bf2f(unsigned short u) {
    union { unsigned int i; float f; } x; x.i = ((unsigned int)u) << 16; return x.f;
}
__device__ __forceinline__ unsigned short f2bf(float f) {
    union { float f; unsigned int i; } x; x.f = f;
    unsigned int i = x.i;
    return (unsigned short)((i + 0x7FFFu + ((i >> 16) & 1u)) >> 16);
}

// ---------------- build Wt[1024][256] bf16 (transposed), biases, gate vecs ----------------
__global__ void k_conv_w(const float* __restrict__ Wq, const float* __restrict__ Wk,
                         const float* __restrict__ Wv, const float* __restrict__ Ws,
                         const float* __restrict__ bq, const float* __restrict__ bk,
                         const float* __restrict__ bv, const float* __restrict__ bs,
                         const float* __restrict__ Wg,
                         unsigned short* __restrict__ Wt, float* __restrict__ ball,
                         float* __restrict__ wga, float* __restrict__ wgb)
{
    int gid = blockIdx.x * 256 + threadIdx.x;  // 65536 threads
    int k = gid >> 8, colq = gid & 255;
    int col0 = colq * 4;
    const float* Wsel[4] = {Wq, Wk, Wv, Ws};
    const float* W = Wsel[col0 >> 8];
    int c0 = col0 & 255;
    f32x4 w = *(const f32x4*)(W + k * 256 + c0);
    for (int j = 0; j < 4; ++j)
        Wt[(size_t)(col0 + j) * 256 + k] = f2bf(w[j]);
    if (gid < 1024) {
        const float* bsel[4] = {bq, bk, bv, bs};
        ball[gid] = bsel[gid >> 8][gid & 255];
    } else if (gid < 1280) {
        int i = gid - 1024;
        wga[i] = Wg[i] + Wg[512 + i];          // coeff on skip
    } else if (gid < 1536) {
        int i = gid - 1280;
        wgb[i] = Wg[256 + i] - Wg[512 + i];    // coeff on rst
    }
}

// ---------------- fused QKV+skip GEMM: feat fp32 [M,256] x Wt [256,1024] ----------------
// R10-proven structure: XCD-cohort swizzle, ONE bn-tile per block (VGPR 64, high occupancy).
// Epilogue writes qkvb row layout q|v|k (col reorder only; dense 2-buffer store shape).
#define BM 128
#define BN 128
#define BK 64
#define SST 72   // LDS row stride in bf16: 144B = 16B-aligned, bank-step 4 -> conflict-free

__global__ __launch_bounds__(256) void k_gemm(
    const float* __restrict__ A, const unsigned short* __restrict__ Bt,
    const float* __restrict__ bias, unsigned short* __restrict__ qkvb,
    float* __restrict__ skipf, int M, int MB)
{
    __shared__ unsigned short a_sm[BM * SST];
    __shared__ unsigned short b_sm[BN * SST];
    int id = blockIdx.x;
    int rr = id & 7, bn = (id >> 3) & 7, bm = (id >> 6) * 8 + rr;  // XCD-cohort swizzle
    if (bm >= MB) return;
    int t = threadIdx.x;
    int lane = t & 63, wid = t >> 6;
    int wr = wid >> 1, wc = wid & 1;
    int l15 = lane & 15, l4 = lane >> 4;
    f32x4 acc[4][4] = {};
    for (int k0 = 0; k0 < 256; k0 += BK) {
        for (int it = 0; it < 4; ++it) {
            int c = it * 256 + t;
            int row = c >> 3;
            int ko = (c & 7) * 8;
            int grow = bm * BM + row;
            if (grow >= M) grow = M - 1;
            const f32x4* pa = (const f32x4*)(A + (size_t)grow * 256 + k0 + ko);
            f32x4 x = pa[0], y = pa[1];
            us8 o;
            o[0] = f2bf(x[0]); o[1] = f2bf(x[1]); o[2] = f2bf(x[2]); o[3] = f2bf(x[3]);
            o[4] = f2bf(y[0]); o[5] = f2bf(y[1]); o[6] = f2bf(y[2]); o[7] = f2bf(y[3]);
            *(us8*)(a_sm + row * SST + ko) = o;
            int gcol = bn * BN + row;
            us8 vb = *(const us8*)(Bt + (size_t)gcol * 256 + k0 + ko);
            *(us8*)(b_sm + row * SST + ko) = vb;
        }
        __syncthreads();
        for (int kk = 0; kk < BK; kk += 32) {
            bf16x8 af[4], bf[4];
            for (int mi = 0; mi < 4; ++mi)
                af[mi] = *(const bf16x8*)(a_sm + (wr * 64 + mi * 16 + l15) * SST + kk + l4 * 8);
            for (int ni = 0; ni < 4; ++ni)
                bf[ni] = *(const bf16x8*)(b_sm + (wc * 64 + ni * 16 + l15) * SST + kk + l4 * 8);
            for (int mi = 0; mi < 4; ++mi)
                for (int ni = 0; ni < 4; ++ni)
                    acc[mi][ni] = __builtin_amdgcn_mfma_f32_16x16x32_bf16(af[mi], bf[ni], acc[mi][ni], 0, 0, 0);
        }
        __syncthreads();
    }
    int colb = bn * BN + wc * 64 + l15;
    for (int mi = 0; mi < 4; ++mi) {
        int rowb = bm * BM + wr * 64 + mi * 16 + l4 * 4;
        for (int ni = 0; ni < 4; ++ni) {
            int col = colb + ni * 16;
            float bv = bias[col];
            // column reorder q|v|k: q stays, k 256-511 -> +256, v 512-767 -> -256
            int ocol = (col < 256) ? col : (col < 512) ? col + 256 : (col < 768) ? col - 256 : col;
            for (int r = 0; r < 4; ++r) {
                int row = rowb + r;
                if (row < M) {
                    float v = acc[mi][ni][r] + bv;
                    if (col < 768) qkvb[(size_t)row * 768 + ocol] = f2bf(v);
                    else skipf[(size_t)row * 256 + (col - 768)] = v;
                }
            }
        }
    }
}

// ---------------- CSR build ----------------
__global__ void k_count(const int* __restrict__ dst, int* __restrict__ cnt, int e) {
    int t = blockIdx.x * 256 + threadIdx.x;
    if (t < e) atomicAdd(&cnt[dst[t]], 1);
}
__global__ void k_scan1(const int* __restrict__ cnt, int* __restrict__ inc, int* __restrict__ bsum, int n) {
    int t = threadIdx.x;
    int i = blockIdx.x * 256 + t;
    int lane = t & 63, w = t >> 6;
    int v = (i < n) ? cnt[i] : 0;
    int s = v;
    for (int off = 1; off < 64; off <<= 1) {
        int u = __shfl_up(s, off, 64);
        if (lane >= off) s += u;
    }
    __shared__ int wt[4];
    if (lane == 63) wt[w] = s;
    __syncthreads();
    for (int j = 0; j < w; ++j) s += wt[j];
    if (i < n) inc[i] = s;
    if (t == 255) bsum[blockIdx.x] = s;
}
__global__ void k_scan2(int* __restrict__ bsum, int nb) {
    int t = threadIdx.x;
    int lane = t & 63, w = t >> 6;
    int v = (t < nb) ? bsum[t] : 0;
    int s = v;
    for (int off = 1; off < 64; off <<= 1) {
        int u = __shfl_up(s, off, 64);
        if (lane >= off) s += u;
    }
    __shared__ int wt[4];
    if (lane == 63) wt[w] = s;
    __syncthreads();
    for (int j = 0; j < w; ++j) s += wt[j];
    if (t < nb) bsum[t] = s - v;
}
__global__ void k_scan3(const int* __restrict__ cnt, int* __restrict__ rowstart, const int* __restrict__ bsum, int n, int e) {
    int i = blockIdx.x * 256 + threadIdx.x;
    if (i < n) rowstart[i] = bsum[blockIdx.x] + rowstart[i] - cnt[i];
    if (i == 0) rowstart[n] = e;
}
__global__ void k_scatter(const int* __restrict__ src, const int* __restrict__ dst,
                          const int* __restrict__ rowstart, int* __restrict__ cur,
                          int* __restrict__ esrc, int e) {
    int t = blockIdx.x * 256 + threadIdx.x;
    if (t < e) {
        int d = dst[t];
        int pos = rowstart[d] + atomicAdd(&cur[d], 1);
        esrc[pos] = src[t];
    }
}

// ---------------- fused attn + gate + LN + PReLU: one wave per dst node ----------------
__device__ __forceinline__ float dot4k(us4 q, const float* kf) {
    return bf2f(q[0]) * kf[0] + bf2f(q[1]) * kf[1] + bf2f(q[2]) * kf[2] + bf2f(q[3]) * kf[3];
}
__device__ __forceinline__ float red16(float sc) {
    sc += __shfl_xor(sc, 1, 16);
    sc += __shfl_xor(sc, 2, 16);
    sc += __shfl_xor(sc, 4, 16);
    sc += __shfl_xor(sc, 8, 16);
    return sc;
}

__global__ void k_attn(const unsigned short* __restrict__ qkvb,
                       const float* __restrict__ skipf,
                       const int* __restrict__ rowstart, const int* __restrict__ esrc,
                       const float* __restrict__ wga, const float* __restrict__ wgb,
                       const float* __restrict__ bgp, const float* __restrict__ lns,
                       const float* __restrict__ lnb, const float* __restrict__ alphap,
                       float* __restrict__ out, int n)
{
    int node = blockIdx.x * 4 + (threadIdx.x >> 6);
    if (node >= n) return;
    int lane = threadIdx.x & 63;
    int lane4 = lane * 4;
    // row layout q|v|k: k for this node at offset 512
    us4 k4 = __builtin_nontemporal_load((const us4*)(qkvb + (size_t)node * 768 + 512 + lane4));
    float kf[4];
    for (int i = 0; i < 4; ++i) kf[i] = bf2f(k4[i]);
    int p0 = rowstart[node], p1 = rowstart[node + 1];
    float denom = 0.f;
    f32x4 acc = {0.f, 0.f, 0.f, 0.f};
    int p = p0;
    for (; p + 8 <= p1; p += 8) {
        int sidx[8];
        #pragma unroll
        for (int j = 0; j < 8; ++j) sidx[j] = esrc[p + j];
        us4 q[8], v[8];
        #pragma unroll
        for (int j = 0; j < 8; ++j) {
            const unsigned short* r = qkvb + (size_t)sidx[j] * 768 + lane4;
            q[j] = *(const us4*)(r);
            v[j] = *(const us4*)(r + 256);
        }
        float a[8];
        #pragma unroll
        for (int j = 0; j < 8; ++j)
            a[j] = __expf(red16(dot4k(q[j], kf)) * 0.125f);
        #pragma unroll
        for (int j = 0; j < 8; ++j) {
            denom += a[j];
            for (int i = 0; i < 4; ++i) acc[i] += a[j] * bf2f(v[j][i]);
        }
    }
    for (; p + 4 <= p1; p += 4) {
        int sidx[4];
        #pragma unroll
        for (int j = 0; j < 4; ++j) sidx[j] = esrc[p + j];
        us4 q[4], v[4];
        #pragma unroll
        for (int j = 0; j < 4; ++j) {
            const unsigned short* r = qkvb + (size_t)sidx[j] * 768 + lane4;
            q[j] = *(const us4*)(r);
            v[j] = *(const us4*)(r + 256);
        }
        float a[4];
        #pragma unroll
        for (int j = 0; j < 4; ++j)
            a[j] = __expf(red16(dot4k(q[j], kf)) * 0.125f);
        #pragma unroll
        for (int j = 0; j < 4; ++j) {
            denom += a[j];
            for (int i = 0; i < 4; ++i) acc[i] += a[j] * bf2f(v[j][i]);
        }
    }
    for (; p < p1; ++p) {
        int s = esrc[p];
        const unsigned short* r = qkvb + (size_t)s * 768 + lane4;
        us4 q4 = *(const us4*)(r);
        us4 v4 = *(const us4*)(r + 256);
        float sc = red16(dot4k(q4, kf));
        float a = __expf(sc * 0.125f);
        denom += a;
        for (int i = 0; i < 4; ++i) acc[i] += a * bf2f(v4[i]);
    }
    float inv = denom > 0.f ? 1.f / denom : 0.f;
    float rst[4];
    for (int i = 0; i < 4; ++i) rst[i] = acc[i] * inv;

    // ---- gate + LN + PReLU (fused epilogue) ----
    f32x4 sk = __builtin_nontemporal_load((const f32x4*)(skipf + (size_t)node * 256 + lane4));
    f32x4 ga = *(const f32x4*)(wga + lane4);
    f32x4 gb = *(const f32x4*)(wgb + lane4);
    float g = 0.f;
    for (int i = 0; i < 4; ++i) g += sk[i] * ga[i] + rst[i] * gb[i];
    for (int off = 1; off < 64; off <<= 1) g += __shfl_xor(g, off, 64);
    float gate = 1.f / (1.f + __expf(-(g + bgp[0])));
    float r[4], s1v = 0.f, s2v = 0.f;
    for (int i = 0; i < 4; ++i) {
        r[i] = gate * sk[i] + (1.f - gate) * rst[i];
        s1v += r[i]; s2v += r[i] * r[i];
    }
    for (int off = 1; off < 64; off <<= 1) {
        s1v += __shfl_xor(s1v, off, 64);
        s2v += __shfl_xor(s2v, off, 64);
    }
    float mean = s1v * (1.f / 256.f);
    float var = s2v * (1.f / 256.f) - mean * mean;
    float rsig = rsqrtf(var + 1e-5f);
    f32x4 sc4 = *(const f32x4*)(lns + lane4);
    f32x4 bi4 = *(const f32x4*)(lnb + lane4);
    float alpha = alphap[0];
    f32x4 y;
    for (int i = 0; i < 4; ++i) {
        float v = (r[i] - mean) * rsig * sc4[i] + bi4[i];
        y[i] = v > 0.f ? v : alpha * v;
    }
    __builtin_nontemporal_store(y, (f32x4*)(out + (size_t)node * 256 + lane4));
}

extern "C" void kernel_launch(void* const* d_in, const int* in_sizes, int n_in,
                              void* d_out, int out_size, void* d_ws, size_t ws_size,
                              hipStream_t stream)
{
    const float* feat = (const float*)d_in[0];
    const int* src = (const int*)d_in[1];
    const int* dst = (const int*)d_in[2];
    const float* Wq = (const float*)d_in[3];
    const float* bq = (const float*)d_in[4];
    const float* Wk = (const float*)d_in[5];
    const float* bk = (const float*)d_in[6];
    const float* Wv = (const float*)d_in[7];
    const float* bv = (const float*)d_in[8];
    const float* Ws = (const float*)d_in[9];
    const float* bs = (const float*)d_in[10];
    const float* Wg = (const float*)d_in[11];
    const float* bg = (const float*)d_in[12];
    const float* lns = (const float*)d_in[13];
    const float* lnb = (const float*)d_in[14];
    const float* alpha = (const float*)d_in[15];
    int N = in_sizes[0] / 256;
    int E = in_sizes[1];

    char* w = (char*)d_ws;
    size_t off = 0;
    auto alloc = [&](size_t b) { char* p = w + off; off += (b + 255) & ~(size_t)255; return p; };
    unsigned short* Wt    = (unsigned short*)alloc((size_t)1024 * 256 * 2);
    float* ball = (float*)alloc(1024 * 4);
    float* wga  = (float*)alloc(256 * 4);
    float* wgb  = (float*)alloc(256 * 4);
    unsigned short* qkvb = (unsigned short*)alloc((size_t)N * 768 * 2);
    float* skipf = (float*)alloc((size_t)N * 256 * 4);
    int* cnt = (int*)alloc((size_t)N * 4);
    int* rowstart = (int*)alloc(((size_t)N + 1) * 4);
    int* bsum = (int*)alloc(256 * 4);
    int* esrc = (int*)alloc((size_t)E * 4);
    float* outf = (float*)d_out;

    hipMemsetAsync(cnt, 0, (size_t)N * 4, stream);

    k_conv_w<<<256, 256, 0, stream>>>(Wq, Wk, Wv, Ws, bq, bk, bv, bs, Wg, Wt, ball, wga, wgb);

    int MB = (N + BM - 1) / BM;                    // 391
    int gridg = ((MB + 7) / 8) * 64;               // 3136, guarded in-kernel
    k_gemm<<<gridg, 256, 0, stream>>>(feat, Wt, ball, qkvb, skipf, N, MB);

    int eb = (E + 255) / 256;
    k_count<<<eb, 256, 0, stream>>>(dst, cnt, E);
    int nb = (N + 255) / 256;
    k_scan1<<<nb, 256, 0, stream>>>(cnt, rowstart, bsum, N);
    k_scan2<<<1, 256, 0, stream>>>(bsum, nb);
    k_scan3<<<nb, 256, 0, stream>>>(cnt, rowstart, bsum, N, E);
    hipMemsetAsync(cnt, 0, (size_t)N * 4, stream);
    k_scatter<<<eb, 256, 0, stream>>>(src, dst, rowstart, cnt, esrc, E);

    k_attn<<<(N + 3) / 4, 256, 0, stream>>>(qkvb, skipf, rowstart, esrc,
                                            wga, wgb, bg, lns, lnb, alpha, outf, N);
}

// Round 14
// 302.195 us; speedup vs baseline: 1.2629x; 1.0063x over previous
//
#include <hip/hip_runtime.h>
#include <hip/hip_bf16.h>

typedef __attribute__((ext_vector_type(4))) float f32x4;
typedef __attribute__((ext_vector_type(8))) short bf16x8;
typedef __attribute__((ext_vector_type(8))) unsigned short us8;
typedef __attribute__((ext_vector_type(4))) unsigned short us4;

__device__ __forceinline__ float bf2f(unsigned short u) {
    union { unsigned int i; float f; } x; x.i = ((unsigned int)u) << 16; return x.f;
}
__device__ __forceinline__ unsigned short f2bf(float f) {
    union { float f; unsigned int i; } x; x.f = f;
    unsigned int i = x.i;
    return (unsigned short)((i + 0x7FFFu + ((i >> 16) & 1u)) >> 16);
}

// ---------------- build Wt[1024][256] bf16 (transposed), biases, gate vecs ----------------
__global__ void k_conv_w(const float* __restrict__ Wq, const float* __restrict__ Wk,
                         const float* __restrict__ Wv, const float* __restrict__ Ws,
                         const float* __restrict__ bq, const float* __restrict__ bk,
                         const float* __restrict__ bv, const float* __restrict__ bs,
                         const float* __restrict__ Wg,
                         unsigned short* __restrict__ Wt, float* __restrict__ ball,
                         float* __restrict__ wga, float* __restrict__ wgb)
{
    int gid = blockIdx.x * 256 + threadIdx.x;  // 65536 threads
    int k = gid >> 8, colq = gid & 255;
    int col0 = colq * 4;
    const float* Wsel[4] = {Wq, Wk, Wv, Ws};
    const float* W = Wsel[col0 >> 8];
    int c0 = col0 & 255;
    f32x4 w = *(const f32x4*)(W + k * 256 + c0);
    for (int j = 0; j < 4; ++j)
        Wt[(size_t)(col0 + j) * 256 + k] = f2bf(w[j]);
    if (gid < 1024) {
        const float* bsel[4] = {bq, bk, bv, bs};
        ball[gid] = bsel[gid >> 8][gid & 255];
    } else if (gid < 1280) {
        int i = gid - 1024;
        wga[i] = Wg[i] + Wg[512 + i];          // coeff on skip
    } else if (gid < 1536) {
        int i = gid - 1280;
        wgb[i] = Wg[256 + i] - Wg[512 + i];    // coeff on rst
    }
}

// ---------------- fused QKV+skip GEMM with register-staged prefetch ----------------
// R10-proven tile/epilogue shape (1 bn-tile, 2 output buffers, q|v|k col reorder).
// NEW: k0+1's global loads are issued before the MFMA phase -> latency hides under MFMA.
#define BM 128
#define BN 128
#define BK 64
#define SST 72   // LDS row stride in bf16: 144B = 16B-aligned, bank-step 4 -> conflict-free

__global__ __launch_bounds__(256) void k_gemm(
    const float* __restrict__ A, const unsigned short* __restrict__ Bt,
    const float* __restrict__ bias, unsigned short* __restrict__ qkvb,
    float* __restrict__ skipf, int M, int MB)
{
    __shared__ unsigned short a_sm[BM * SST];
    __shared__ unsigned short b_sm[BN * SST];
    int id = blockIdx.x;
    int rr = id & 7, bn = (id >> 3) & 7, bm = (id >> 6) * 8 + rr;  // XCD-cohort swizzle
    if (bm >= MB) return;
    int t = threadIdx.x;
    int lane = t & 63, wid = t >> 6;
    int wr = wid >> 1, wc = wid & 1;
    int l15 = lane & 15, l4 = lane >> 4;

    // per-thread staging coordinates (4 chunks)
    int srow[4], sko[4];
    const float* pa[4];
    const unsigned short* pb[4];
    for (int it = 0; it < 4; ++it) {
        int c = it * 256 + t;
        int row = c >> 3, ko = (c & 7) * 8;
        srow[it] = row; sko[it] = ko;
        int grow = bm * BM + row;
        if (grow >= M) grow = M - 1;
        pa[it] = A + (size_t)grow * 256 + ko;
        pb[it] = Bt + (size_t)(bn * BN + row) * 256 + ko;
    }

    f32x4 rax[4], ray[4];
    us8 rb[4];
    auto load_regs = [&](int k0) {
        #pragma unroll
        for (int it = 0; it < 4; ++it) {
            const f32x4* p = (const f32x4*)(pa[it] + k0);
            rax[it] = p[0]; ray[it] = p[1];
            rb[it] = *(const us8*)(pb[it] + k0);
        }
    };

    f32x4 acc[4][4] = {};
    load_regs(0);
    for (int k0 = 0; k0 < 256; k0 += BK) {
        // write staged registers to LDS
        #pragma unroll
        for (int it = 0; it < 4; ++it) {
            us8 o;
            o[0] = f2bf(rax[it][0]); o[1] = f2bf(rax[it][1]);
            o[2] = f2bf(rax[it][2]); o[3] = f2bf(rax[it][3]);
            o[4] = f2bf(ray[it][0]); o[5] = f2bf(ray[it][1]);
            o[6] = f2bf(ray[it][2]); o[7] = f2bf(ray[it][3]);
            *(us8*)(a_sm + srow[it] * SST + sko[it]) = o;
            *(us8*)(b_sm + srow[it] * SST + sko[it]) = rb[it];
        }
        __syncthreads();
        if (k0 + BK < 256) load_regs(k0 + BK);   // issue next loads; latency hides under MFMA
        for (int kk = 0; kk < BK; kk += 32) {
            bf16x8 af[4], bf[4];
            for (int mi = 0; mi < 4; ++mi)
                af[mi] = *(const bf16x8*)(a_sm + (wr * 64 + mi * 16 + l15) * SST + kk + l4 * 8);
            for (int ni = 0; ni < 4; ++ni)
                bf[ni] = *(const bf16x8*)(b_sm + (wc * 64 + ni * 16 + l15) * SST + kk + l4 * 8);
            for (int mi = 0; mi < 4; ++mi)
                for (int ni = 0; ni < 4; ++ni)
                    acc[mi][ni] = __builtin_amdgcn_mfma_f32_16x16x32_bf16(af[mi], bf[ni], acc[mi][ni], 0, 0, 0);
        }
        __syncthreads();
    }
    int colb = bn * BN + wc * 64 + l15;
    for (int mi = 0; mi < 4; ++mi) {
        int rowb = bm * BM + wr * 64 + mi * 16 + l4 * 4;
        for (int ni = 0; ni < 4; ++ni) {
            int col = colb + ni * 16;
            float bv = bias[col];
            // column reorder q|v|k: q stays, k 256-511 -> +256, v 512-767 -> -256
            int ocol = (col < 256) ? col : (col < 512) ? col + 256 : (col < 768) ? col - 256 : col;
            for (int r = 0; r < 4; ++r) {
                int row = rowb + r;
                if (row < M) {
                    float v = acc[mi][ni][r] + bv;
                    if (col < 768) qkvb[(size_t)row * 768 + ocol] = f2bf(v);
                    else skipf[(size_t)row * 256 + (col - 768)] = v;
                }
            }
        }
    }
}

// ---------------- CSR build ----------------
__global__ void k_count(const int* __restrict__ dst, int* __restrict__ cnt, int e) {
    int t = blockIdx.x * 256 + threadIdx.x;
    if (t < e) atomicAdd(&cnt[dst[t]], 1);
}
__global__ void k_scan1(const int* __restrict__ cnt, int* __restrict__ inc, int* __restrict__ bsum, int n) {
    int t = threadIdx.x;
    int i = blockIdx.x * 256 + t;
    int lane = t & 63, w = t >> 6;
    int v = (i < n) ? cnt[i] : 0;
    int s = v;
    for (int off = 1; off < 64; off <<= 1) {
        int u = __shfl_up(s, off, 64);
        if (lane >= off) s += u;
    }
    __shared__ int wt[4];
    if (lane == 63) wt[w] = s;
    __syncthreads();
    for (int j = 0; j < w; ++j) s += wt[j];
    if (i < n) inc[i] = s;
    if (t == 255) bsum[blockIdx.x] = s;
}
// scan3 computes its own exclusive block offset from bsum (scan2 eliminated)
__global__ void k_scan3(const int* __restrict__ cnt, int* __restrict__ rowstart,
                        const int* __restrict__ bsum, int n, int e) {
    int t = threadIdx.x;
    int bid = blockIdx.x;
    int lane = t & 63, w = t >> 6;
    int v = (t < bid) ? bsum[t] : 0;       // nb <= 256 blocks
    for (int off = 32; off > 0; off >>= 1) v += __shfl_xor(v, off, 64);
    __shared__ int wt[4];
    if (lane == 0) wt[w] = v;
    __syncthreads();
    int off0 = wt[0] + wt[1] + wt[2] + wt[3];
    int i = bid * 256 + t;
    if (i < n) rowstart[i] = off0 + rowstart[i] - cnt[i];
    if (i == 0) rowstart[n] = e;
}
__global__ void k_scatter(const int* __restrict__ src, const int* __restrict__ dst,
                          const int* __restrict__ rowstart, int* __restrict__ cur,
                          int* __restrict__ esrc, int e) {
    int t = blockIdx.x * 256 + threadIdx.x;
    if (t < e) {
        int d = dst[t];
        int pos = rowstart[d] + atomicAdd(&cur[d], 1);
        esrc[pos] = src[t];
    }
}

// ---------------- fused attn + gate + LN + PReLU: one wave per dst node ----------------
__device__ __forceinline__ float dot4k(us4 q, const float* kf) {
    return bf2f(q[0]) * kf[0] + bf2f(q[1]) * kf[1] + bf2f(q[2]) * kf[2] + bf2f(q[3]) * kf[3];
}
__device__ __forceinline__ float red16(float sc) {
    sc += __shfl_xor(sc, 1, 16);
    sc += __shfl_xor(sc, 2, 16);
    sc += __shfl_xor(sc, 4, 16);
    sc += __shfl_xor(sc, 8, 16);
    return sc;
}

__global__ void k_attn(const unsigned short* __restrict__ qkvb,
                       const float* __restrict__ skipf,
                       const int* __restrict__ rowstart, const int* __restrict__ esrc,
                       const float* __restrict__ wga, const float* __restrict__ wgb,
                       const float* __restrict__ bgp, const float* __restrict__ lns,
                       const float* __restrict__ lnb, const float* __restrict__ alphap,
                       float* __restrict__ out, int n)
{
    int node = blockIdx.x * 4 + (threadIdx.x >> 6);
    if (node >= n) return;
    int lane = threadIdx.x & 63;
    int lane4 = lane * 4;
    // row layout q|v|k: k for this node at offset 512
    us4 k4 = __builtin_nontemporal_load((const us4*)(qkvb + (size_t)node * 768 + 512 + lane4));
    float kf[4];
    for (int i = 0; i < 4; ++i) kf[i] = bf2f(k4[i]);
    int p0 = rowstart[node], p1 = rowstart[node + 1];
    float denom = 0.f;
    f32x4 acc = {0.f, 0.f, 0.f, 0.f};
    int p = p0;
    for (; p + 8 <= p1; p += 8) {
        int sidx[8];
        #pragma unroll
        for (int j = 0; j < 8; ++j) sidx[j] = esrc[p + j];
        us4 q[8], v[8];
        #pragma unroll
        for (int j = 0; j < 8; ++j) {
            const unsigned short* r = qkvb + (size_t)sidx[j] * 768 + lane4;
            q[j] = *(const us4*)(r);
            v[j] = *(const us4*)(r + 256);
        }
        float a[8];
        #pragma unroll
        for (int j = 0; j < 8; ++j)
            a[j] = __expf(red16(dot4k(q[j], kf)) * 0.125f);
        #pragma unroll
        for (int j = 0; j < 8; ++j) {
            denom += a[j];
            for (int i = 0; i < 4; ++i) acc[i] += a[j] * bf2f(v[j][i]);
        }
    }
    for (; p + 4 <= p1; p += 4) {
        int sidx[4];
        #pragma unroll
        for (int j = 0; j < 4; ++j) sidx[j] = esrc[p + j];
        us4 q[4], v[4];
        #pragma unroll
        for (int j = 0; j < 4; ++j) {
            const unsigned short* r = qkvb + (size_t)sidx[j] * 768 + lane4;
            q[j] = *(const us4*)(r);
            v[j] = *(const us4*)(r + 256);
        }
        float a[4];
        #pragma unroll
        for (int j = 0; j < 4; ++j)
            a[j] = __expf(red16(dot4k(q[j], kf)) * 0.125f);
        #pragma unroll
        for (int j = 0; j < 4; ++j) {
            denom += a[j];
            for (int i = 0; i < 4; ++i) acc[i] += a[j] * bf2f(v[j][i]);
        }
    }
    for (; p < p1; ++p) {
        int s = esrc[p];
        const unsigned short* r = qkvb + (size_t)s * 768 + lane4;
        us4 q4 = *(const us4*)(r);
        us4 v4 = *(const us4*)(r + 256);
        float sc = red16(dot4k(q4, kf));
        float a = __expf(sc * 0.125f);
        denom += a;
        for (int i = 0; i < 4; ++i) acc[i] += a * bf2f(v4[i]);
    }
    float inv = denom > 0.f ? 1.f / denom : 0.f;
    float rst[4];
    for (int i = 0; i < 4; ++i) rst[i] = acc[i] * inv;

    // ---- gate + LN + PReLU (fused epilogue) ----
    f32x4 sk = __builtin_nontemporal_load((const f32x4*)(skipf + (size_t)node * 256 + lane4));
    f32x4 ga = *(const f32x4*)(wga + lane4);
    f32x4 gb = *(const f32x4*)(wgb + lane4);
    float g = 0.f;
    for (int i = 0; i < 4; ++i) g += sk[i] * ga[i] + rst[i] * gb[i];
    for (int off = 1; off < 64; off <<= 1) g += __shfl_xor(g, off, 64);
    float gate = 1.f / (1.f + __expf(-(g + bgp[0])));
    float r[4], s1v = 0.f, s2v = 0.f;
    for (int i = 0; i < 4; ++i) {
        r[i] = gate * sk[i] + (1.f - gate) * rst[i];
        s1v += r[i]; s2v += r[i] * r[i];
    }
    for (int off = 1; off < 64; off <<= 1) {
        s1v += __shfl_xor(s1v, off, 64);
        s2v += __shfl_xor(s2v, off, 64);
    }
    float mean = s1v * (1.f / 256.f);
    float var = s2v * (1.f / 256.f) - mean * mean;
    float rsig = rsqrtf(var + 1e-5f);
    f32x4 sc4 = *(const f32x4*)(lns + lane4);
    f32x4 bi4 = *(const f32x4*)(lnb + lane4);
    float alpha = alphap[0];
    f32x4 y;
    for (int i = 0; i < 4; ++i) {
        float v = (r[i] - mean) * rsig * sc4[i] + bi4[i];
        y[i] = v > 0.f ? v : alpha * v;
    }
    __builtin_nontemporal_store(y, (f32x4*)(out + (size_t)node * 256 + lane4));
}

extern "C" void kernel_launch(void* const* d_in, const int* in_sizes, int n_in,
                              void* d_out, int out_size, void* d_ws, size_t ws_size,
                              hipStream_t stream)
{
    const float* feat = (const float*)d_in[0];
    const int* src = (const int*)d_in[1];
    const int* dst = (const int*)d_in[2];
    const float* Wq = (const float*)d_in[3];
    const float* bq = (const float*)d_in[4];
    const float* Wk = (const float*)d_in[5];
    const float* bk = (const float*)d_in[6];
    const float* Wv = (const float*)d_in[7];
    const float* bv = (const float*)d_in[8];
    const float* Ws = (const float*)d_in[9];
    const float* bs = (const float*)d_in[10];
    const float* Wg = (const float*)d_in[11];
    const float* bg = (const float*)d_in[12];
    const float* lns = (const float*)d_in[13];
    const float* lnb = (const float*)d_in[14];
    const float* alpha = (const float*)d_in[15];
    int N = in_sizes[0] / 256;
    int E = in_sizes[1];

    char* w = (char*)d_ws;
    size_t off = 0;
    auto alloc = [&](size_t b) { char* p = w + off; off += (b + 255) & ~(size_t)255; return p; };
    unsigned short* Wt    = (unsigned short*)alloc((size_t)1024 * 256 * 2);
    float* ball = (float*)alloc(1024 * 4);
    float* wga  = (float*)alloc(256 * 4);
    float* wgb  = (float*)alloc(256 * 4);
    unsigned short* qkvb = (unsigned short*)alloc((size_t)N * 768 * 2);
    float* skipf = (float*)alloc((size_t)N * 256 * 4);
    int* cnt = (int*)alloc((size_t)N * 2 * 4);   // cnt (N) + cur (N), zeroed together
    int* cur = cnt + N;
    int* rowstart = (int*)alloc(((size_t)N + 1) * 4);
    int* bsum = (int*)alloc(256 * 4);
    int* esrc = (int*)alloc((size_t)E * 4);
    float* outf = (float*)d_out;

    hipMemsetAsync(cnt, 0, (size_t)N * 2 * 4, stream);

    k_conv_w<<<256, 256, 0, stream>>>(Wq, Wk, Wv, Ws, bq, bk, bv, bs, Wg, Wt, ball, wga, wgb);

    int MB = (N + BM - 1) / BM;                    // 391
    int gridg = ((MB + 7) / 8) * 64;               // 3136, guarded in-kernel
    k_gemm<<<gridg, 256, 0, stream>>>(feat, Wt, ball, qkvb, skipf, N, MB);

    int eb = (E + 255) / 256;
    k_count<<<eb, 256, 0, stream>>>(dst, cnt, E);
    int nb = (N + 255) / 256;
    k_scan1<<<nb, 256, 0, stream>>>(cnt, rowstart, bsum, N);
    k_scan3<<<nb, 256, 0, stream>>>(cnt, rowstart, bsum, N, E);
    k_scatter<<<eb, 256, 0, stream>>>(src, dst, rowstart, cur, esrc, E);

    k_attn<<<(N + 3) / 4, 256, 0, stream>>>(qkvb, skipf, rowstart, esrc,
                                            wga, wgb, bg, lns, lnb, alpha, outf, N);
}